// Round 9
// baseline (362.663 us; speedup 1.0000x reference)
//
#include <hip/hip_runtime.h>
#include <hip/hip_bf16.h>
#include <math.h>

#define B_ 2
#define L_ 2048
#define D_ 1024
#define QH_ 8
#define KVH_ 2
#define HD_ 128
#define FFN_ 4096
#define T_ (B_ * L_)
#define EPS_ 1.1920929e-07f

typedef __bf16 bf16x8 __attribute__((ext_vector_type(8)));
typedef float floatx4 __attribute__((ext_vector_type(4)));
typedef unsigned short ushortx8 __attribute__((ext_vector_type(8)));
typedef unsigned short ushortx4 __attribute__((ext_vector_type(4)));

__device__ __forceinline__ unsigned short f2bf(float f) {
  union { float f; unsigned int u; } v;
  v.f = f;
  unsigned int r = v.u + 0x7FFFu + ((v.u >> 16) & 1u);
  return (unsigned short)(r >> 16);
}
__device__ __forceinline__ float bf2f(unsigned short u) {
  union { unsigned int u; float f; } v;
  v.u = ((unsigned int)u) << 16;
  return v.f;
}
__device__ __forceinline__ void gload_lds16(const void* g, void* l) {
  __builtin_amdgcn_global_load_lds((const __attribute__((address_space(1))) void*)g,
                                   (__attribute__((address_space(3))) void*)l, 16, 0, 0);
}

// ---------------------------------------------------------------------------
// 32x128 transpose+cast strip (4 k-tiles): in fp32 [K,N] -> out bf16 [N,K].
// ---------------------------------------------------------------------------
__device__ __forceinline__ void strip_tc(const float* __restrict__ in,
                                         unsigned short* __restrict__ out,
                                         int K, int N, int n0, int k0) {
  __shared__ float tile[4][32][33];
  int t = threadIdx.x;
  int tx = t & 31, ty = t >> 5;
#pragma unroll
  for (int s = 0; s < 4; s++)
#pragma unroll
    for (int r0 = 0; r0 < 4; r0++) {
      int r = ty + r0 * 8;
      tile[s][r][tx] = in[(size_t)(k0 + s * 32 + r) * N + n0 + tx];
    }
  __syncthreads();
  int nr = t >> 3, kq = t & 7;
#pragma unroll
  for (int s = 0; s < 4; s++) {
    ushortx4 o4;
#pragma unroll
    for (int j = 0; j < 4; j++) o4[j] = f2bf(tile[s][kq * 4 + j][nr]);
    *(ushortx4*)(out + (size_t)(n0 + nr) * K + k0 + s * 32 + kq * 4) = o4;
  }
}

// ---------------------------------------------------------------------------
// RMSNorm row -> bf16
// ---------------------------------------------------------------------------
__device__ __forceinline__ void rmsnorm_row(const float* __restrict__ x,
                                            const float* __restrict__ w,
                                            unsigned short* __restrict__ o, int row) {
  __shared__ float red[4];
  int t = threadIdx.x;
  const float* xr = x + (size_t)row * D_;
  float4 xv = *(const float4*)(xr + t * 4);
  float ss = xv.x * xv.x + xv.y * xv.y + xv.z * xv.z + xv.w * xv.w;
#pragma unroll
  for (int off = 32; off >= 1; off >>= 1) ss += __shfl_xor(ss, off);
  if ((t & 63) == 0) red[t >> 6] = ss;
  __syncthreads();
  float total = red[0] + red[1] + red[2] + red[3];
  float r = rsqrtf(total * (1.0f / (float)D_) + EPS_);
  float4 wv = *(const float4*)(w + t * 4);
  unsigned short* op = o + (size_t)row * D_ + t * 4;
  op[0] = f2bf(xv.x * r * wv.x);
  op[1] = f2bf(xv.y * r * wv.y);
  op[2] = f2bf(xv.z * r * wv.z);
  op[3] = f2bf(xv.w * r * wv.w);
}

// ---------------------------------------------------------------------------
// prep_all: 7 weight transposes as 3712 4-tile strips + rmsnorm1 (4096 rows)
// + rope sin/cos table fill (512 blocks): tab[pos][d2] = {sin,cos}(pos*ts^-1).
// ---------------------------------------------------------------------------
__global__ __launch_bounds__(256) void prep_all(
    const float* __restrict__ wq, const float* __restrict__ wk,
    const float* __restrict__ wv, const float* __restrict__ wo,
    const float* __restrict__ wg, const float* __restrict__ wu,
    const float* __restrict__ wd, unsigned short* __restrict__ wT,
    const float* __restrict__ x, const float* __restrict__ ln1w,
    unsigned short* __restrict__ h_bf, float* __restrict__ rope_tab) {
  int bid = blockIdx.x;
  if (bid < 3712) {
    const float* in;
    unsigned short* out;
    int K, N, nt, base;
    if (bid < 256)       { in = wq; out = wT;            K = 1024; N = 1024; nt = 32;  base = 0; }
    else if (bid < 320)  { in = wk; out = wT + 1048576;  K = 1024; N = 256;  nt = 8;   base = 256; }
    else if (bid < 384)  { in = wv; out = wT + 1310720;  K = 1024; N = 256;  nt = 8;   base = 320; }
    else if (bid < 640)  { in = wo; out = wT + 1572864;  K = 1024; N = 1024; nt = 32;  base = 384; }
    else if (bid < 1664) { in = wg; out = wT + 2621440;  K = 1024; N = 4096; nt = 128; base = 640; }
    else if (bid < 2688) { in = wu; out = wT + 6815744;  K = 1024; N = 4096; nt = 128; base = 1664; }
    else                 { in = wd; out = wT + 11010048; K = 4096; N = 1024; nt = 32;  base = 2688; }
    int idx = bid - base;
    strip_tc(in, out, K, N, (idx % nt) * 32, (idx / nt) * 128);
  } else if (bid < 3712 + T_) {
    rmsnorm_row(x, ln1w, h_bf, bid - 3712);
  } else {
    // rope table: 2048 pos x 64 d2, one entry per thread
    int e = (bid - 3712 - T_) * 256 + threadIdx.x;  // 0..131071
    int pos = e >> 6, d2 = e & 63;
    float inv_ts = expf(-0.14391156831f * (float)d2);
    float rad = (float)pos * inv_ts;
    float2 sc = make_float2(sinf(rad), cosf(rad));
    *(float2*)(rope_tab + (size_t)e * 2) = sc;
  }
}

__global__ __launch_bounds__(256) void rmsnorm_bf16_kernel(const float* __restrict__ x,
                                                           const float* __restrict__ w,
                                                           unsigned short* __restrict__ o) {
  rmsnorm_row(x, w, o, blockIdx.x);
}

// ---------------------------------------------------------------------------
// bf16 MFMA GEMM, BK = 32*KH, XOR-swizzled conflict-free LDS.
// Tile = 64 x 128 (MW=32), 2x2 waves.  Optional split-K via blockIdx.z
// (each z-slice covers K/gridDim.z; EPI==2 accumulates via atomicAdd so
// slices combine order-independently).
// EPI: 1 = C=v+R fp32 (gridDim.z==1); 2 = C += v (atomic).  Kloc % (32*KH)==0.
// ---------------------------------------------------------------------------
template <int EPI, int KH>
__global__ __launch_bounds__(256, 3) void gemm_bf16(const unsigned short* __restrict__ A,
                                                    const unsigned short* __restrict__ BT,
                                                    const float* __restrict__ R,
                                                    float* __restrict__ C,
                                                    int M, int N, int K) {
  __shared__ unsigned short As[KH][64 * 32];
  __shared__ unsigned short Bs[KH][128 * 32];
  int t = threadIdx.x;
  int lane = t & 63, wave = t >> 6;
  int m0 = blockIdx.y * 64, n0 = blockIdx.x * 128;
  int Kloc = K / gridDim.z;
  size_t koff = (size_t)blockIdx.z * Kloc;

  int row_a = t >> 2;
  int kc = ((t & 3) ^ ((t >> 3) & 3)) * 8;
  const unsigned short* ga0 = A + (size_t)(m0 + row_a) * K + koff + kc;
  const unsigned short* gb0 = BT + (size_t)(n0 + row_a) * K + koff + kc;
  const unsigned short* gb1 = BT + (size_t)(n0 + 64 + row_a) * K + koff + kc;

  int wm = (wave & 1) * 32, wn = (wave >> 1) * 64;
  int fr = lane & 15, quad = lane >> 4;
  int sw = (quad ^ ((fr >> 1) & 3)) * 8;

  floatx4 acc[2][4];
#pragma unroll
  for (int i = 0; i < 2; i++)
#pragma unroll
    for (int j = 0; j < 4; j++) acc[i][j] = (floatx4){0.f, 0.f, 0.f, 0.f};

  for (int k0 = 0; k0 < Kloc; k0 += 32 * KH) {
#pragma unroll
    for (int h = 0; h < KH; h++) {
      int ko = k0 + h * 32;
      gload_lds16(ga0 + ko, As[h] + wave * 512);
      gload_lds16(gb0 + ko, Bs[h] + wave * 512);
      gload_lds16(gb1 + ko, Bs[h] + 2048 + wave * 512);
    }
    __syncthreads();
#pragma unroll
    for (int h = 0; h < KH; h++) {
      const unsigned short* arp = As[h] + (size_t)(wm + fr) * 32 + sw;
      const unsigned short* brp = Bs[h] + (size_t)(wn + fr) * 32 + sw;
      bf16x8 af[2], bfr[4];
#pragma unroll
      for (int i = 0; i < 2; i++)
        af[i] = __builtin_bit_cast(bf16x8, *(const ushortx8*)(arp + i * 16 * 32));
#pragma unroll
      for (int j = 0; j < 4; j++)
        bfr[j] = __builtin_bit_cast(bf16x8, *(const ushortx8*)(brp + j * 16 * 32));
#pragma unroll
      for (int i = 0; i < 2; i++)
#pragma unroll
        for (int j = 0; j < 4; j++)
          acc[i][j] = __builtin_amdgcn_mfma_f32_16x16x32_bf16(af[i], bfr[j], acc[i][j], 0, 0, 0);
    }
    __syncthreads();
  }

  int orow = m0 + wm + quad * 4;
  int ocol = n0 + wn + fr;
#pragma unroll
  for (int i = 0; i < 2; i++) {
#pragma unroll
    for (int r = 0; r < 4; r++) {
      int row = orow + i * 16 + r;
#pragma unroll
      for (int j = 0; j < 4; j++) {
        size_t idx = (size_t)row * N + ocol + j * 16;
        float v = acc[i][j][r];
        if (EPI == 1) C[idx] = v + R[idx];
        else atomicAdd(&C[idx], v);
      }
    }
  }
}

// ---------------------------------------------------------------------------
// QKV GEMM with fused rope/transpose epilogue.  Tile 64x128, BK=128 (KH=4).
// Rope sin/cos from precomputed table (L2-resident 1 MB).
// ---------------------------------------------------------------------------
__global__ __launch_bounds__(256) void gemm_qkv(const unsigned short* __restrict__ A,
                                                const unsigned short* __restrict__ BT,
                                                unsigned short* __restrict__ qb,
                                                unsigned short* __restrict__ Kb,
                                                unsigned short* __restrict__ Vt,
                                                const float* __restrict__ rope_tab) {
  constexpr int K = 1024;
  __shared__ unsigned short smem[24576];  // 48 KB -> 3 blocks/CU
  int t = threadIdx.x;
  int lane = t & 63, wave = t >> 6;
  int bx = blockIdx.x;
  int m0 = blockIdx.y * 64, n0 = bx * 128;

  int row_a = t >> 2;
  int kc = ((t & 3) ^ ((t >> 3) & 3)) * 8;
  const unsigned short* ga0 = A + (size_t)(m0 + row_a) * K + kc;
  const unsigned short* gb0 = BT + (size_t)(n0 + row_a) * K + kc;
  const unsigned short* gb1 = BT + (size_t)(n0 + 64 + row_a) * K + kc;

  int wm = (wave & 1) * 32, wn = (wave >> 1) * 64;
  int fr = lane & 15, quad = lane >> 4;
  int sw = (quad ^ ((fr >> 1) & 3)) * 8;

  floatx4 acc[2][4];
#pragma unroll
  for (int i = 0; i < 2; i++)
#pragma unroll
    for (int j = 0; j < 4; j++) acc[i][j] = (floatx4){0.f, 0.f, 0.f, 0.f};

  for (int k0 = 0; k0 < K; k0 += 128) {
#pragma unroll
    for (int h = 0; h < 4; h++) {
      int ko = k0 + h * 32;
      gload_lds16(ga0 + ko, smem + h * 2048 + wave * 512);
      gload_lds16(gb0 + ko, smem + 8192 + h * 4096 + wave * 512);
      gload_lds16(gb1 + ko, smem + 8192 + h * 4096 + 2048 + wave * 512);
    }
    __syncthreads();
#pragma unroll
    for (int h = 0; h < 4; h++) {
      const unsigned short* arp = smem + h * 2048 + (size_t)(wm + fr) * 32 + sw;
      const unsigned short* brp = smem + 8192 + h * 4096 + (size_t)(wn + fr) * 32 + sw;
      bf16x8 af[2], bfr[4];
#pragma unroll
      for (int i = 0; i < 2; i++)
        af[i] = __builtin_bit_cast(bf16x8, *(const ushortx8*)(arp + i * 16 * 32));
#pragma unroll
      for (int j = 0; j < 4; j++)
        bfr[j] = __builtin_bit_cast(bf16x8, *(const ushortx8*)(brp + j * 16 * 32));
#pragma unroll
      for (int i = 0; i < 2; i++)
#pragma unroll
        for (int j = 0; j < 4; j++)
          acc[i][j] = __builtin_amdgcn_mfma_f32_16x16x32_bf16(af[i], bfr[j], acc[i][j], 0, 0, 0);
    }
    __syncthreads();
  }

  unsigned short* scr = smem;
#pragma unroll
  for (int i = 0; i < 2; i++)
#pragma unroll
    for (int r = 0; r < 4; r++)
#pragma unroll
      for (int j = 0; j < 4; j++)
        scr[(size_t)(wm + quad * 4 + i * 16 + r) * 136 + wn + fr + j * 16] =
            f2bf(acc[i][j][r]);
  __syncthreads();

  if (bx < 10) {
    int row = t >> 2, dq = (t & 3) * 16;
    int tok = m0 + row, pos = tok & (L_ - 1), b = tok >> 11;
    float scale_ = (bx < 8) ? 0.08838834764831843f : 1.0f;
    const float2* rt = (const float2*)rope_tab + (size_t)pos * 64 + dq;
    unsigned short lo[16], hi[16];
#pragma unroll
    for (int m = 0; m < 16; m++) {
      int d2 = dq + m;
      float x1 = bf2f(scr[(size_t)row * 136 + d2]);
      float x2 = bf2f(scr[(size_t)row * 136 + d2 + 64]);
      float2 sc = rt[m];
      float s = sc.x, c = sc.y;
      lo[m] = f2bf((x1 * c - x2 * s) * scale_);
      hi[m] = f2bf((x2 * c + x1 * s) * scale_);
    }
    if (bx < 8) {
      unsigned short* dst = qb + (size_t)tok * 1024 + bx * 128;
      *(ushortx8*)(dst + dq) = *(const ushortx8*)(lo);
      *(ushortx8*)(dst + dq + 8) = *(const ushortx8*)(lo + 8);
      *(ushortx8*)(dst + 64 + dq) = *(const ushortx8*)(hi);
      *(ushortx8*)(dst + 64 + dq + 8) = *(const ushortx8*)(hi + 8);
    } else {
      int kvh = bx - 8, bk = b * KVH_ + kvh, swk = pos & 15;
      unsigned short* dst = Kb + ((size_t)bk * L_ + pos) * HD_;
      int c0 = dq >> 3;
      *(ushortx8*)(dst + ((c0) ^ swk) * 8) = *(const ushortx8*)(lo);
      *(ushortx8*)(dst + ((c0 + 1) ^ swk) * 8) = *(const ushortx8*)(lo + 8);
      *(ushortx8*)(dst + ((c0 + 8) ^ swk) * 8) = *(const ushortx8*)(hi);
      *(ushortx8*)(dst + ((c0 + 9) ^ swk) * 8) = *(const ushortx8*)(hi + 8);
    }
  } else {
    int kvh = bx - 10;
    int b = m0 >> 11, key0 = m0 & (L_ - 1), bk = b * KVH_ + kvh;
    int hd = t >> 1, half = t & 1;
#pragma unroll
    for (int c = 0; c < 4; c++) {
      int cp = half * 4 + c, kcc = cp ^ (hd & 7);
      ushortx8 ob;
#pragma unroll
      for (int j = 0; j < 8; j++) ob[j] = scr[(size_t)(kcc * 8 + j) * 136 + hd];
      *(ushortx8*)(Vt + ((size_t)bk * HD_ + hd) * L_ + key0 + cp * 8) = ob;
    }
  }
}

// ---------------------------------------------------------------------------
// Fused gate+up GEMM: 8-phase counted-vmcnt (best measured variant, R6).
// ---------------------------------------------------------------------------
__global__ __launch_bounds__(512, 1) void gemm_gateup8p(
    const unsigned short* __restrict__ A,
    const unsigned short* __restrict__ BgT,
    const unsigned short* __restrict__ BuT,
    unsigned short* __restrict__ Cb) {
  constexpr int K = 1024;
  __shared__ unsigned short As0[2][8192];
  __shared__ unsigned short As1[2][8192];
  __shared__ unsigned short Bs0[2][8192];
  __shared__ unsigned short Bs1[2][8192];

  int t = threadIdx.x;
  int lane = t & 63, wave = t >> 6;
  int m0 = blockIdx.y * 256;
  int n0l = blockIdx.x * 128;

  int row_s = t >> 2;
  int kc = ((t & 3) ^ ((t >> 3) & 3)) * 8;
  const unsigned short* gaB[2];
  gaB[0] = A + (size_t)(m0 + row_s) * K + kc;
  gaB[1] = A + (size_t)(m0 + 128 + row_s) * K + kc;
  const unsigned short* gbB[2];
#pragma unroll
  for (int hf = 0; hf < 2; hf++) {
    int rb = hf * 128 + row_s;
    const unsigned short* src = ((rb & 31) < 16) ? BgT : BuT;
    gbB[hf] = src + (size_t)(n0l + (rb >> 5) * 16 + (rb & 15)) * K + kc;
  }

  int wm = wave >> 2, wn = wave & 3;
  int fr = lane & 15, quad = lane >> 4;
  int sw = (quad ^ ((fr >> 1) & 3)) * 8;
  int aro = (wm * 128 + fr) * 32 + sw;
  int bro = (wn * 64 + fr) * 32 + sw;

  floatx4 acc[8][4];
#pragma unroll
  for (int i = 0; i < 8; i++)
#pragma unroll
    for (int j = 0; j < 4; j++) acc[i][j] = (floatx4){0.f, 0.f, 0.f, 0.f};

  bf16x8 af[4][2], b0[2][2], b1[2][2];

#define GU_AS(b_) ((b_) ? As1 : As0)
#define GU_BS(b_) ((b_) ? Bs1 : Bs0)

#define GU_LDA(buf_, ilo_)                                                          \
  { _Pragma("unroll") for (int i_ = 0; i_ < 4; i_++) {                              \
      af[i_][0] = __builtin_bit_cast(                                               \
          bf16x8, *(const ushortx8*)(&GU_AS(buf_)[0][aro + ((ilo_) + i_) * 512]));  \
      af[i_][1] = __builtin_bit_cast(                                               \
          bf16x8, *(const ushortx8*)(&GU_AS(buf_)[1][aro + ((ilo_) + i_) * 512])); } }

#define GU_LDB(buf_, jlo_, bp_)                                                     \
  { _Pragma("unroll") for (int j_ = 0; j_ < 2; j_++) {                              \
      bp_[j_][0] = __builtin_bit_cast(                                              \
          bf16x8, *(const ushortx8*)(&GU_BS(buf_)[0][bro + ((jlo_) + j_) * 512]));  \
      bp_[j_][1] = __builtin_bit_cast(                                              \
          bf16x8, *(const ushortx8*)(&GU_BS(buf_)[1][bro + ((jlo_) + j_) * 512])); } }

#define GU_MM(ilo_, jlo_, bp_)                                                    \
  { __builtin_amdgcn_s_setprio(1);                                                \
    _Pragma("unroll") for (int i_ = 0; i_ < 4; i_++)                              \
        _Pragma("unroll") for (int j_ = 0; j_ < 2; j_++) {                        \
      acc[(ilo_) + i_][(jlo_) + j_] = __builtin_amdgcn_mfma_f32_16x16x32_bf16(    \
          af[i_][0], bp_[j_][0], acc[(ilo_) + i_][(jlo_) + j_], 0, 0, 0);         \
      acc[(ilo_) + i_][(jlo_) + j_] = __builtin_amdgcn_mfma_f32_16x16x32_bf16(    \
          af[i_][1], bp_[j_][1], acc[(ilo_) + i_][(jlo_) + j_], 0, 0, 0); }       \
    __builtin_amdgcn_s_setprio(0); }

#define GU_STA(buf_, tile_, half_)                                                \
  { const unsigned short* g_ = gaB[half_] + (size_t)(tile_) * 64;                 \
    gload_lds16(g_, &GU_AS(buf_)[0][(half_) * 4096 + wave * 512]);                \
    gload_lds16(g_ + 32, &GU_AS(buf_)[1][(half_) * 4096 + wave * 512]); }

#define GU_STB(buf_, tile_, half_)                                                \
  { const unsigned short* g_ = gbB[half_] + (size_t)(tile_) * 64;                 \
    gload_lds16(g_, &GU_BS(buf_)[0][(half_) * 4096 + wave * 512]);                \
    gload_lds16(g_ + 32, &GU_BS(buf_)[1][(half_) * 4096 + wave * 512]); }

#define GU_BAR __builtin_amdgcn_s_barrier()
#define GU_LGKM0 asm volatile("s_waitcnt lgkmcnt(0)" ::: "memory")
#define GU_VM6 asm volatile("s_waitcnt vmcnt(6)" ::: "memory")
#define GU_VM0 asm volatile("s_waitcnt vmcnt(0)" ::: "memory")

  GU_STB(0, 0, 0); GU_STB(0, 0, 1);
  GU_STA(0, 0, 0); GU_STA(0, 0, 1);
  GU_STB(1, 1, 0); GU_STB(1, 1, 1);
  GU_STA(1, 1, 0);
  GU_VM6;
  GU_BAR;

#pragma unroll 1
  for (int n = 0; n < 7; n++) {
    int tO = 2 * n + 1, tE2 = 2 * n + 2, tO2 = 2 * n + 3;
    GU_LDA(0, 0); GU_LDB(0, 0, b0); GU_STA(1, tO, 1);
    GU_BAR; GU_LGKM0; GU_MM(0, 0, b0); GU_BAR;
    GU_LDB(0, 2, b1);
    GU_BAR; GU_LGKM0; GU_MM(0, 2, b1); GU_BAR;
    GU_LDA(0, 4); GU_STB(0, tE2, 0);
    GU_BAR; GU_LGKM0; GU_MM(4, 0, b0); GU_BAR;
    GU_STB(0, tE2, 1); GU_STA(0, tE2, 0);
    GU_VM6;
    GU_BAR; GU_LGKM0; GU_MM(4, 2, b1); GU_BAR;
    GU_LDA(1, 0); GU_LDB(1, 0, b0); GU_STA(0, tE2, 1);
    GU_BAR; GU_LGKM0; GU_MM(0, 0, b0); GU_BAR;
    GU_LDB(1, 2, b1);
    GU_BAR; GU_LGKM0; GU_MM(0, 2, b1); GU_BAR;
    GU_LDA(1, 4); GU_STB(1, tO2, 0);
    GU_BAR; GU_LGKM0; GU_MM(4, 0, b0); GU_BAR;
    GU_STB(1, tO2, 1); GU_STA(1, tO2, 0);
    GU_VM6;
    GU_BAR; GU_LGKM0; GU_MM(4, 2, b1); GU_BAR;
  }
  GU_LDA(0, 0); GU_LDB(0, 0, b0); GU_STA(1, 15, 1);
  GU_BAR; GU_LGKM0; GU_MM(0, 0, b0); GU_BAR;
  GU_LDB(0, 2, b1);
  GU_BAR; GU_LGKM0; GU_MM(0, 2, b1); GU_BAR;
  GU_LDA(0, 4);
  GU_BAR; GU_LGKM0; GU_MM(4, 0, b0); GU_BAR;
  GU_VM0;
  GU_BAR; GU_LGKM0; GU_MM(4, 2, b1); GU_BAR;
  GU_LDA(1, 0); GU_LDB(1, 0, b0);
  GU_BAR; GU_LGKM0; GU_MM(0, 0, b0); GU_BAR;
  GU_LDB(1, 2, b1);
  GU_BAR; GU_LGKM0; GU_MM(0, 2, b1); GU_BAR;
  GU_LDA(1, 4);
  GU_BAR; GU_LGKM0; GU_MM(4, 0, b0); GU_BAR;
  GU_MM(4, 2, b1);

#undef GU_LDA
#undef GU_LDB
#undef GU_MM
#undef GU_STA
#undef GU_STB
#undef GU_AS
#undef GU_BS
#undef GU_BAR
#undef GU_LGKM0
#undef GU_VM6
#undef GU_VM0

#pragma unroll
  for (int i = 0; i < 8; i++) {
    int row = m0 + wm * 128 + i * 16 + quad * 4;
#pragma unroll
    for (int r = 0; r < 4; r++) {
#pragma unroll
      for (int jj = 0; jj < 2; jj++) {
        float g = acc[i][2 * jj][r];
        float u = acc[i][2 * jj + 1][r];
        int colL = n0l + (wn * 2 + jj) * 16 + fr;
        Cb[(size_t)(row + r) * FFN_ + colL] = f2bf(g / (1.f + __expf(-g)) * u);
      }
    }
  }
}

// ---------------------------------------------------------------------------
// MFMA flash attention, no-max softmax; Q pre-roped+pre-scaled bf16 [T][1024].
// ---------------------------------------------------------------------------
__global__ __launch_bounds__(256) void attn_mfma(const unsigned short* __restrict__ qb,
                                                 const unsigned short* __restrict__ Kb,
                                                 const unsigned short* __restrict__ Vt,
                                                 unsigned short* __restrict__ ctx) {
  __shared__ unsigned short Ks[64 * 128];
  __shared__ unsigned short Vs[128 * 64];
  __shared__ unsigned short Ps[4][16 * 72];
  int id = blockIdx.x;
  int bh = id & 15;
  int p_ = id >> 4;
  int qt = (p_ < 16) ? p_ : 47 - p_;
  int b = bh >> 3, h = bh & 7;
  int bk = b * KVH_ + (h >> 2);
  int q0 = qt * 64;
  int t = threadIdx.x, lane = t & 63, w = t >> 6;
  int fr = lane & 15, quad = lane >> 4;

  int pos = q0 + w * 16 + fr;
  const unsigned short* qrow = qb + (size_t)(b * L_ + pos) * 1024 + h * HD_;
  bf16x8 qf[4];
#pragma unroll
  for (int kb = 0; kb < 4; kb++)
    qf[kb] = __builtin_bit_cast(bf16x8, *(const ushortx8*)(qrow + kb * 32 + quad * 8));

  floatx4 o_acc[8];
#pragma unroll
  for (int nt = 0; nt < 8; nt++) o_acc[nt] = (floatx4){0.f, 0.f, 0.f, 0.f};
  float l_r[4] = {0.f, 0.f, 0.f, 0.f};
  unsigned short* Psw = Ps[w];
  const unsigned short* kgb = Kb + (size_t)bk * L_ * HD_;
  const unsigned short* vgb = Vt + (size_t)bk * HD_ * L_;
  int rowg0 = q0 + w * 16 + quad * 4;

  for (int kt = 0; kt <= qt; kt++) {
    int kstart = kt * 64;
    bool diag = (kt == qt);
    __syncthreads();
    const unsigned short* ksrc = kgb + (size_t)kstart * HD_;
#pragma unroll
    for (int it = 0; it < 4; it++) {
      int sl = it * 4 + w;
      gload_lds16(ksrc + sl * 512 + lane * 8, Ks + sl * 512);
    }
#pragma unroll
    for (int it = 0; it < 4; it++) {
      int sl = it * 4 + w;
      gload_lds16(vgb + (size_t)(sl * 8 + (lane >> 3)) * L_ + kstart + (lane & 7) * 8,
                  Vs + sl * 512);
    }
    __syncthreads();

    floatx4 s_acc[4];
#pragma unroll
    for (int jt = 0; jt < 4; jt++) s_acc[jt] = (floatx4){0.f, 0.f, 0.f, 0.f};
#pragma unroll
    for (int kb = 0; kb < 4; kb++) {
#pragma unroll
      for (int jt = 0; jt < 4; jt++) {
        bf16x8 kf = __builtin_bit_cast(
            bf16x8, *(const ushortx8*)(Ks + (jt * 16 + fr) * 128 +
                                       (((kb * 4 + quad) ^ fr) * 8)));
        s_acc[jt] = __builtin_amdgcn_mfma_f32_16x16x32_bf16(qf[kb], kf, s_acc[jt], 0, 0, 0);
      }
    }

#pragma unroll
    for (int jt = 0; jt < 4; jt++) {
#pragma unroll
      for (int r = 0; r < 4; r++) {
        float pp;
        if (diag) {
          int keyg = kstart + jt * 16 + fr;
          pp = (keyg <= rowg0 + r) ? __expf(s_acc[jt][r]) : 0.f;
        } else {
          pp = __expf(s_acc[jt][r]);
        }
        l_r[r] += pp;
        Psw[(quad * 4 + r) * 72 + jt * 16 + fr] = f2bf(pp);
      }
    }
    bf16x8 pf0 = __builtin_bit_cast(bf16x8, *(const ushortx8*)(Psw + fr * 72 + quad * 8));
    bf16x8 pf1 =
        __builtin_bit_cast(bf16x8, *(const ushortx8*)(Psw + fr * 72 + 32 + quad * 8));
#pragma unroll
    for (int nt = 0; nt < 8; nt++) {
      bf16x8 vf0 = __builtin_bit_cast(
          bf16x8,
          *(const ushortx8*)(Vs + (nt * 16 + fr) * 64 + ((quad ^ (fr & 7)) * 8)));
      bf16x8 vf1 = __builtin_bit_cast(
          bf16x8,
          *(const ushortx8*)(Vs + (nt * 16 + fr) * 64 + (((4 + quad) ^ (fr & 7)) * 8)));
      o_acc[nt] = __builtin_amdgcn_mfma_f32_16x16x32_bf16(pf0, vf0, o_acc[nt], 0, 0, 0);
      o_acc[nt] = __builtin_amdgcn_mfma_f32_16x16x32_bf16(pf1, vf1, o_acc[nt], 0, 0, 0);
    }
  }

#pragma unroll
  for (int r = 0; r < 4; r++) {
    l_r[r] += __shfl_xor(l_r[r], 1);
    l_r[r] += __shfl_xor(l_r[r], 2);
    l_r[r] += __shfl_xor(l_r[r], 4);
    l_r[r] += __shfl_xor(l_r[r], 8);
  }

  unsigned short* ob =
      ctx + (size_t)(b * L_ + q0 + w * 16 + quad * 4) * 1024 + h * HD_ + fr;
#pragma unroll
  for (int r = 0; r < 4; r++) {
    float inv = 1.f / l_r[r];
    unsigned short* orow = ob + (size_t)r * 1024;
#pragma unroll
    for (int nt = 0; nt < 8; nt++) orow[nt * 16] = f2bf(o_acc[nt][r] * inv);
  }
}

// ---------------------------------------------------------------------------
extern "C" void kernel_launch(void* const* d_in, const int* in_sizes, int n_in,
                              void* d_out, int out_size, void* d_ws, size_t ws_size,
                              hipStream_t stream) {
  const float* x    = (const float*)d_in[0];
  const float* ln1w = (const float*)d_in[1];
  const float* wq   = (const float*)d_in[2];
  const float* wk   = (const float*)d_in[3];
  const float* wvp  = (const float*)d_in[4];
  const float* wo   = (const float*)d_in[5];
  const float* ln2w = (const float*)d_in[6];
  const float* wg   = (const float*)d_in[7];
  const float* wu   = (const float*)d_in[8];
  const float* wd   = (const float*)d_in[9];
  float* out = (float*)d_out;
  char* ws = (char*)d_ws;

  // workspace layout (bytes), ~91 MB total:
  unsigned short* wT = (unsigned short*)ws;                       // 30,408,704 B
  unsigned short* wqkvT = wT;                                     // [1536][1024]
  unsigned short* woT = wT + 1572864;                             // [1024][1024]
  unsigned short* wgT = wT + 2621440;                             // [4096][1024]
  unsigned short* wuT = wT + 6815744;                             // [4096][1024]
  unsigned short* wdT = wT + 11010048;                            // [1024][4096]
  unsigned short* h_bf = (unsigned short*)(ws + 30408704);        // 8 MB (ctx_bf reuse)
  unsigned short* qb = (unsigned short*)(ws + 38797312);          // [4096][1024] roped Q, 8 MB
  float* rope_tab = (float*)(ws + 47185920);                      // 1 MB sin/cos table
  unsigned short* h2_bf = (unsigned short*)(ws + 51380224);       // 8 MB
  unsigned short* Kb = (unsigned short*)(ws + 59768832);          // 2 MB (attn phase)
  unsigned short* Vt = (unsigned short*)(ws + 61865984);          // 2 MB (attn phase)
  unsigned short* gu = (unsigned short*)(ws + 59768832);          // 32 MB (FFN phase)
  unsigned short* ctx_bf = h_bf;

  dim3 blk(256);

  // 1. weight transposes + rmsnorm1 + rope sin/cos table (512 blocks)
  prep_all<<<3712 + T_ + 512, blk, 0, stream>>>(wq, wk, wvp, wo, wg, wu, wd, wT,
                                                x, ln1w, h_bf, rope_tab);
  // 2. fused QKV GEMM (BK=128) + rope(Q,K via table) + V transpose
  gemm_qkv<<<dim3(12, 64), blk, 0, stream>>>(h_bf, wqkvT, qb, Kb, Vt, rope_tab);
  // 3. attention (no-max softmax, Q pre-roped)
  attn_mfma<<<512, blk, 0, stream>>>(qb, Kb, Vt, ctx_bf);
  // 4. out = ctx @ wo + x   (64x128 tile, BK=128)
  gemm_bf16<1, 4><<<dim3(8, 64), blk, 0, stream>>>(ctx_bf, woT, x, out, T_, 1024, 1024);
  // 5. rmsnorm2 on out
  rmsnorm_bf16_kernel<<<T_, blk, 0, stream>>>(out, ln2w, h2_bf);
  // 6. gate+up fused: 8-phase counted-vmcnt (best measured variant)
  gemm_gateup8p<<<dim3(32, 16), dim3(512), 0, stream>>>(h2_bf, wgT, wuT, gu);
  // 7. out += gu @ wd — split-K=2 (1024 blocks -> 3/CU), atomicAdd combine
  gemm_bf16<2, 4><<<dim3(8, 64, 2), blk, 0, stream>>>(gu, wdT, nullptr, out, T_, 1024, FFN_);
}

// Round 10
// 346.777 us; speedup vs baseline: 1.0458x; 1.0458x over previous
//
#include <hip/hip_runtime.h>
#include <hip/hip_bf16.h>
#include <math.h>

#define B_ 2
#define L_ 2048
#define D_ 1024
#define QH_ 8
#define KVH_ 2
#define HD_ 128
#define FFN_ 4096
#define T_ (B_ * L_)
#define EPS_ 1.1920929e-07f

typedef __bf16 bf16x8 __attribute__((ext_vector_type(8)));
typedef float floatx4 __attribute__((ext_vector_type(4)));
typedef unsigned short ushortx8 __attribute__((ext_vector_type(8)));
typedef unsigned short ushortx4 __attribute__((ext_vector_type(4)));

__device__ __forceinline__ unsigned short f2bf(float f) {
  union { float f; unsigned int u; } v;
  v.f = f;
  unsigned int r = v.u + 0x7FFFu + ((v.u >> 16) & 1u);
  return (unsigned short)(r >> 16);
}
__device__ __forceinline__ float bf2f(unsigned short u) {
  union { unsigned int u; float f; } v;
  v.u = ((unsigned int)u) << 16;
  return v.f;
}
__device__ __forceinline__ void gload_lds16(const void* g, void* l) {
  __builtin_amdgcn_global_load_lds((const __attribute__((address_space(1))) void*)g,
                                   (__attribute__((address_space(3))) void*)l, 16, 0, 0);
}

// ---------------------------------------------------------------------------
// 32x128 transpose+cast strip (4 k-tiles): in fp32 [K,N] -> out bf16 [N,K].
// ---------------------------------------------------------------------------
__device__ __forceinline__ void strip_tc(const float* __restrict__ in,
                                         unsigned short* __restrict__ out,
                                         int K, int N, int n0, int k0) {
  __shared__ float tile[4][32][33];
  int t = threadIdx.x;
  int tx = t & 31, ty = t >> 5;
#pragma unroll
  for (int s = 0; s < 4; s++)
#pragma unroll
    for (int r0 = 0; r0 < 4; r0++) {
      int r = ty + r0 * 8;
      tile[s][r][tx] = in[(size_t)(k0 + s * 32 + r) * N + n0 + tx];
    }
  __syncthreads();
  int nr = t >> 3, kq = t & 7;
#pragma unroll
  for (int s = 0; s < 4; s++) {
    ushortx4 o4;
#pragma unroll
    for (int j = 0; j < 4; j++) o4[j] = f2bf(tile[s][kq * 4 + j][nr]);
    *(ushortx4*)(out + (size_t)(n0 + nr) * K + k0 + s * 32 + kq * 4) = o4;
  }
}

// ---------------------------------------------------------------------------
// RMSNorm row -> bf16
// ---------------------------------------------------------------------------
__device__ __forceinline__ void rmsnorm_row(const float* __restrict__ x,
                                            const float* __restrict__ w,
                                            unsigned short* __restrict__ o, int row) {
  __shared__ float red[4];
  int t = threadIdx.x;
  const float* xr = x + (size_t)row * D_;
  float4 xv = *(const float4*)(xr + t * 4);
  float ss = xv.x * xv.x + xv.y * xv.y + xv.z * xv.z + xv.w * xv.w;
#pragma unroll
  for (int off = 32; off >= 1; off >>= 1) ss += __shfl_xor(ss, off);
  if ((t & 63) == 0) red[t >> 6] = ss;
  __syncthreads();
  float total = red[0] + red[1] + red[2] + red[3];
  float r = rsqrtf(total * (1.0f / (float)D_) + EPS_);
  float4 wv = *(const float4*)(w + t * 4);
  unsigned short* op = o + (size_t)row * D_ + t * 4;
  op[0] = f2bf(xv.x * r * wv.x);
  op[1] = f2bf(xv.y * r * wv.y);
  op[2] = f2bf(xv.z * r * wv.z);
  op[3] = f2bf(xv.w * r * wv.w);
}

// ---------------------------------------------------------------------------
// prep_all: 7 weight transposes as 3712 4-tile strips + rmsnorm1 (4096 rows)
// + rope sin/cos table fill (512 blocks): tab[pos][d2] = {sin,cos}(pos*ts^-1).
// ---------------------------------------------------------------------------
__global__ __launch_bounds__(256) void prep_all(
    const float* __restrict__ wq, const float* __restrict__ wk,
    const float* __restrict__ wv, const float* __restrict__ wo,
    const float* __restrict__ wg, const float* __restrict__ wu,
    const float* __restrict__ wd, unsigned short* __restrict__ wT,
    const float* __restrict__ x, const float* __restrict__ ln1w,
    unsigned short* __restrict__ h_bf, float* __restrict__ rope_tab) {
  int bid = blockIdx.x;
  if (bid < 3712) {
    const float* in;
    unsigned short* out;
    int K, N, nt, base;
    if (bid < 256)       { in = wq; out = wT;            K = 1024; N = 1024; nt = 32;  base = 0; }
    else if (bid < 320)  { in = wk; out = wT + 1048576;  K = 1024; N = 256;  nt = 8;   base = 256; }
    else if (bid < 384)  { in = wv; out = wT + 1310720;  K = 1024; N = 256;  nt = 8;   base = 320; }
    else if (bid < 640)  { in = wo; out = wT + 1572864;  K = 1024; N = 1024; nt = 32;  base = 384; }
    else if (bid < 1664) { in = wg; out = wT + 2621440;  K = 1024; N = 4096; nt = 128; base = 640; }
    else if (bid < 2688) { in = wu; out = wT + 6815744;  K = 1024; N = 4096; nt = 128; base = 1664; }
    else                 { in = wd; out = wT + 11010048; K = 4096; N = 1024; nt = 32;  base = 2688; }
    int idx = bid - base;
    strip_tc(in, out, K, N, (idx % nt) * 32, (idx / nt) * 128);
  } else if (bid < 3712 + T_) {
    rmsnorm_row(x, ln1w, h_bf, bid - 3712);
  } else {
    // rope table: 2048 pos x 64 d2, one entry per thread
    int e = (bid - 3712 - T_) * 256 + threadIdx.x;  // 0..131071
    int pos = e >> 6, d2 = e & 63;
    float inv_ts = expf(-0.14391156831f * (float)d2);
    float rad = (float)pos * inv_ts;
    float2 sc = make_float2(sinf(rad), cosf(rad));
    *(float2*)(rope_tab + (size_t)e * 2) = sc;
  }
}

__global__ __launch_bounds__(256) void rmsnorm_bf16_kernel(const float* __restrict__ x,
                                                           const float* __restrict__ w,
                                                           unsigned short* __restrict__ o) {
  rmsnorm_row(x, w, o, blockIdx.x);
}

// ---------------------------------------------------------------------------
// bf16 MFMA GEMM, BK = 32*KH, XOR-swizzled conflict-free LDS.
// Tile = 64 x 128 (MW=32), 2x2 waves.
// Grid mapping: blockIdx.x = ROW tile, blockIdx.y = COLUMN tile (grid (M/64,
// N/128)).  With round-robin block->XCD assignment (id = bx + by*gx, XCD =
// id%8), each XCD pins gx/8 A row-panels in its L2 (A fetched ~once
// globally) and streams the small B matrix — right asymmetry when A >> B
// (wd: A=32MB, B=8MB; measured 136MB FETCH with the old column-fastest map).
// EPI: 1 = C=v+R fp32; 2 = C=v+C in-place fp32.  K % (32*KH) == 0.
// ---------------------------------------------------------------------------
template <int EPI, int KH>
__global__ __launch_bounds__(256, 3) void gemm_bf16(const unsigned short* __restrict__ A,
                                                    const unsigned short* __restrict__ BT,
                                                    const float* __restrict__ R,
                                                    float* __restrict__ C,
                                                    int M, int N, int K) {
  __shared__ unsigned short As[KH][64 * 32];
  __shared__ unsigned short Bs[KH][128 * 32];
  int t = threadIdx.x;
  int lane = t & 63, wave = t >> 6;
  int m0 = blockIdx.x * 64, n0 = blockIdx.y * 128;

  int row_a = t >> 2;
  int kc = ((t & 3) ^ ((t >> 3) & 3)) * 8;
  const unsigned short* ga0 = A + (size_t)(m0 + row_a) * K + kc;
  const unsigned short* gb0 = BT + (size_t)(n0 + row_a) * K + kc;
  const unsigned short* gb1 = BT + (size_t)(n0 + 64 + row_a) * K + kc;

  int wm = (wave & 1) * 32, wn = (wave >> 1) * 64;
  int fr = lane & 15, quad = lane >> 4;
  int sw = (quad ^ ((fr >> 1) & 3)) * 8;

  floatx4 acc[2][4];
#pragma unroll
  for (int i = 0; i < 2; i++)
#pragma unroll
    for (int j = 0; j < 4; j++) acc[i][j] = (floatx4){0.f, 0.f, 0.f, 0.f};

  for (int k0 = 0; k0 < K; k0 += 32 * KH) {
#pragma unroll
    for (int h = 0; h < KH; h++) {
      int ko = k0 + h * 32;
      gload_lds16(ga0 + ko, As[h] + wave * 512);
      gload_lds16(gb0 + ko, Bs[h] + wave * 512);
      gload_lds16(gb1 + ko, Bs[h] + 2048 + wave * 512);
    }
    __syncthreads();
#pragma unroll
    for (int h = 0; h < KH; h++) {
      const unsigned short* arp = As[h] + (size_t)(wm + fr) * 32 + sw;
      const unsigned short* brp = Bs[h] + (size_t)(wn + fr) * 32 + sw;
      bf16x8 af[2], bfr[4];
#pragma unroll
      for (int i = 0; i < 2; i++)
        af[i] = __builtin_bit_cast(bf16x8, *(const ushortx8*)(arp + i * 16 * 32));
#pragma unroll
      for (int j = 0; j < 4; j++)
        bfr[j] = __builtin_bit_cast(bf16x8, *(const ushortx8*)(brp + j * 16 * 32));
#pragma unroll
      for (int i = 0; i < 2; i++)
#pragma unroll
        for (int j = 0; j < 4; j++)
          acc[i][j] = __builtin_amdgcn_mfma_f32_16x16x32_bf16(af[i], bfr[j], acc[i][j], 0, 0, 0);
    }
    __syncthreads();
  }

  int orow = m0 + wm + quad * 4;
  int ocol = n0 + wn + fr;
#pragma unroll
  for (int i = 0; i < 2; i++) {
#pragma unroll
    for (int r = 0; r < 4; r++) {
      int row = orow + i * 16 + r;
#pragma unroll
      for (int j = 0; j < 4; j++) {
        size_t idx = (size_t)row * N + ocol + j * 16;
        float v = acc[i][j][r];
        if (EPI == 1) C[idx] = v + R[idx];
        else C[idx] = v + C[idx];
      }
    }
  }
}

// ---------------------------------------------------------------------------
// QKV GEMM with fused rope/transpose epilogue.  Tile 64x128, BK=128 (KH=4).
// Rope sin/cos from precomputed table (L2-resident 1 MB).
// ---------------------------------------------------------------------------
__global__ __launch_bounds__(256) void gemm_qkv(const unsigned short* __restrict__ A,
                                                const unsigned short* __restrict__ BT,
                                                unsigned short* __restrict__ qb,
                                                unsigned short* __restrict__ Kb,
                                                unsigned short* __restrict__ Vt,
                                                const float* __restrict__ rope_tab) {
  constexpr int K = 1024;
  __shared__ unsigned short smem[24576];  // 48 KB -> 3 blocks/CU
  int t = threadIdx.x;
  int lane = t & 63, wave = t >> 6;
  int bx = blockIdx.x;
  int m0 = blockIdx.y * 64, n0 = bx * 128;

  int row_a = t >> 2;
  int kc = ((t & 3) ^ ((t >> 3) & 3)) * 8;
  const unsigned short* ga0 = A + (size_t)(m0 + row_a) * K + kc;
  const unsigned short* gb0 = BT + (size_t)(n0 + row_a) * K + kc;
  const unsigned short* gb1 = BT + (size_t)(n0 + 64 + row_a) * K + kc;

  int wm = (wave & 1) * 32, wn = (wave >> 1) * 64;
  int fr = lane & 15, quad = lane >> 4;
  int sw = (quad ^ ((fr >> 1) & 3)) * 8;

  floatx4 acc[2][4];
#pragma unroll
  for (int i = 0; i < 2; i++)
#pragma unroll
    for (int j = 0; j < 4; j++) acc[i][j] = (floatx4){0.f, 0.f, 0.f, 0.f};

  for (int k0 = 0; k0 < K; k0 += 128) {
#pragma unroll
    for (int h = 0; h < 4; h++) {
      int ko = k0 + h * 32;
      gload_lds16(ga0 + ko, smem + h * 2048 + wave * 512);
      gload_lds16(gb0 + ko, smem + 8192 + h * 4096 + wave * 512);
      gload_lds16(gb1 + ko, smem + 8192 + h * 4096 + 2048 + wave * 512);
    }
    __syncthreads();
#pragma unroll
    for (int h = 0; h < 4; h++) {
      const unsigned short* arp = smem + h * 2048 + (size_t)(wm + fr) * 32 + sw;
      const unsigned short* brp = smem + 8192 + h * 4096 + (size_t)(wn + fr) * 32 + sw;
      bf16x8 af[2], bfr[4];
#pragma unroll
      for (int i = 0; i < 2; i++)
        af[i] = __builtin_bit_cast(bf16x8, *(const ushortx8*)(arp + i * 16 * 32));
#pragma unroll
      for (int j = 0; j < 4; j++)
        bfr[j] = __builtin_bit_cast(bf16x8, *(const ushortx8*)(brp + j * 16 * 32));
#pragma unroll
      for (int i = 0; i < 2; i++)
#pragma unroll
        for (int j = 0; j < 4; j++)
          acc[i][j] = __builtin_amdgcn_mfma_f32_16x16x32_bf16(af[i], bfr[j], acc[i][j], 0, 0, 0);
    }
    __syncthreads();
  }

  unsigned short* scr = smem;
#pragma unroll
  for (int i = 0; i < 2; i++)
#pragma unroll
    for (int r = 0; r < 4; r++)
#pragma unroll
      for (int j = 0; j < 4; j++)
        scr[(size_t)(wm + quad * 4 + i * 16 + r) * 136 + wn + fr + j * 16] =
            f2bf(acc[i][j][r]);
  __syncthreads();

  if (bx < 10) {
    int row = t >> 2, dq = (t & 3) * 16;
    int tok = m0 + row, pos = tok & (L_ - 1), b = tok >> 11;
    float scale_ = (bx < 8) ? 0.08838834764831843f : 1.0f;
    const float2* rt = (const float2*)rope_tab + (size_t)pos * 64 + dq;
    unsigned short lo[16], hi[16];
#pragma unroll
    for (int m = 0; m < 16; m++) {
      int d2 = dq + m;
      float x1 = bf2f(scr[(size_t)row * 136 + d2]);
      float x2 = bf2f(scr[(size_t)row * 136 + d2 + 64]);
      float2 sc = rt[m];
      float s = sc.x, c = sc.y;
      lo[m] = f2bf((x1 * c - x2 * s) * scale_);
      hi[m] = f2bf((x2 * c + x1 * s) * scale_);
    }
    if (bx < 8) {
      unsigned short* dst = qb + (size_t)tok * 1024 + bx * 128;
      *(ushortx8*)(dst + dq) = *(const ushortx8*)(lo);
      *(ushortx8*)(dst + dq + 8) = *(const ushortx8*)(lo + 8);
      *(ushortx8*)(dst + 64 + dq) = *(const ushortx8*)(hi);
      *(ushortx8*)(dst + 64 + dq + 8) = *(const ushortx8*)(hi + 8);
    } else {
      int kvh = bx - 8, bk = b * KVH_ + kvh, swk = pos & 15;
      unsigned short* dst = Kb + ((size_t)bk * L_ + pos) * HD_;
      int c0 = dq >> 3;
      *(ushortx8*)(dst + ((c0) ^ swk) * 8) = *(const ushortx8*)(lo);
      *(ushortx8*)(dst + ((c0 + 1) ^ swk) * 8) = *(const ushortx8*)(lo + 8);
      *(ushortx8*)(dst + ((c0 + 8) ^ swk) * 8) = *(const ushortx8*)(hi);
      *(ushortx8*)(dst + ((c0 + 9) ^ swk) * 8) = *(const ushortx8*)(hi + 8);
    }
  } else {
    int kvh = bx - 10;
    int b = m0 >> 11, key0 = m0 & (L_ - 1), bk = b * KVH_ + kvh;
    int hd = t >> 1, half = t & 1;
#pragma unroll
    for (int c = 0; c < 4; c++) {
      int cp = half * 4 + c, kcc = cp ^ (hd & 7);
      ushortx8 ob;
#pragma unroll
      for (int j = 0; j < 8; j++) ob[j] = scr[(size_t)(kcc * 8 + j) * 136 + hd];
      *(ushortx8*)(Vt + ((size_t)bk * HD_ + hd) * L_ + key0 + cp * 8) = ob;
    }
  }
}

// ---------------------------------------------------------------------------
// Fused gate+up GEMM: 8-phase counted-vmcnt (best measured variant, R6).
// ---------------------------------------------------------------------------
__global__ __launch_bounds__(512, 1) void gemm_gateup8p(
    const unsigned short* __restrict__ A,
    const unsigned short* __restrict__ BgT,
    const unsigned short* __restrict__ BuT,
    unsigned short* __restrict__ Cb) {
  constexpr int K = 1024;
  __shared__ unsigned short As0[2][8192];
  __shared__ unsigned short As1[2][8192];
  __shared__ unsigned short Bs0[2][8192];
  __shared__ unsigned short Bs1[2][8192];

  int t = threadIdx.x;
  int lane = t & 63, wave = t >> 6;
  int m0 = blockIdx.y * 256;
  int n0l = blockIdx.x * 128;

  int row_s = t >> 2;
  int kc = ((t & 3) ^ ((t >> 3) & 3)) * 8;
  const unsigned short* gaB[2];
  gaB[0] = A + (size_t)(m0 + row_s) * K + kc;
  gaB[1] = A + (size_t)(m0 + 128 + row_s) * K + kc;
  const unsigned short* gbB[2];
#pragma unroll
  for (int hf = 0; hf < 2; hf++) {
    int rb = hf * 128 + row_s;
    const unsigned short* src = ((rb & 31) < 16) ? BgT : BuT;
    gbB[hf] = src + (size_t)(n0l + (rb >> 5) * 16 + (rb & 15)) * K + kc;
  }

  int wm = wave >> 2, wn = wave & 3;
  int fr = lane & 15, quad = lane >> 4;
  int sw = (quad ^ ((fr >> 1) & 3)) * 8;
  int aro = (wm * 128 + fr) * 32 + sw;
  int bro = (wn * 64 + fr) * 32 + sw;

  floatx4 acc[8][4];
#pragma unroll
  for (int i = 0; i < 8; i++)
#pragma unroll
    for (int j = 0; j < 4; j++) acc[i][j] = (floatx4){0.f, 0.f, 0.f, 0.f};

  bf16x8 af[4][2], b0[2][2], b1[2][2];

#define GU_AS(b_) ((b_) ? As1 : As0)
#define GU_BS(b_) ((b_) ? Bs1 : Bs0)

#define GU_LDA(buf_, ilo_)                                                          \
  { _Pragma("unroll") for (int i_ = 0; i_ < 4; i_++) {                              \
      af[i_][0] = __builtin_bit_cast(                                               \
          bf16x8, *(const ushortx8*)(&GU_AS(buf_)[0][aro + ((ilo_) + i_) * 512]));  \
      af[i_][1] = __builtin_bit_cast(                                               \
          bf16x8, *(const ushortx8*)(&GU_AS(buf_)[1][aro + ((ilo_) + i_) * 512])); } }

#define GU_LDB(buf_, jlo_, bp_)                                                     \
  { _Pragma("unroll") for (int j_ = 0; j_ < 2; j_++) {                              \
      bp_[j_][0] = __builtin_bit_cast(                                              \
          bf16x8, *(const ushortx8*)(&GU_BS(buf_)[0][bro + ((jlo_) + j_) * 512]));  \
      bp_[j_][1] = __builtin_bit_cast(                                              \
          bf16x8, *(const ushortx8*)(&GU_BS(buf_)[1][bro + ((jlo_) + j_) * 512])); } }

#define GU_MM(ilo_, jlo_, bp_)                                                    \
  { __builtin_amdgcn_s_setprio(1);                                                \
    _Pragma("unroll") for (int i_ = 0; i_ < 4; i_++)                              \
        _Pragma("unroll") for (int j_ = 0; j_ < 2; j_++) {                        \
      acc[(ilo_) + i_][(jlo_) + j_] = __builtin_amdgcn_mfma_f32_16x16x32_bf16(    \
          af[i_][0], bp_[j_][0], acc[(ilo_) + i_][(jlo_) + j_], 0, 0, 0);         \
      acc[(ilo_) + i_][(jlo_) + j_] = __builtin_amdgcn_mfma_f32_16x16x32_bf16(    \
          af[i_][1], bp_[j_][1], acc[(ilo_) + i_][(jlo_) + j_], 0, 0, 0); }       \
    __builtin_amdgcn_s_setprio(0); }

#define GU_STA(buf_, tile_, half_)                                                \
  { const unsigned short* g_ = gaB[half_] + (size_t)(tile_) * 64;                 \
    gload_lds16(g_, &GU_AS(buf_)[0][(half_) * 4096 + wave * 512]);                \
    gload_lds16(g_ + 32, &GU_AS(buf_)[1][(half_) * 4096 + wave * 512]); }

#define GU_STB(buf_, tile_, half_)                                                \
  { const unsigned short* g_ = gbB[half_] + (size_t)(tile_) * 64;                 \
    gload_lds16(g_, &GU_BS(buf_)[0][(half_) * 4096 + wave * 512]);                \
    gload_lds16(g_ + 32, &GU_BS(buf_)[1][(half_) * 4096 + wave * 512]); }

#define GU_BAR __builtin_amdgcn_s_barrier()
#define GU_LGKM0 asm volatile("s_waitcnt lgkmcnt(0)" ::: "memory")
#define GU_VM6 asm volatile("s_waitcnt vmcnt(6)" ::: "memory")
#define GU_VM0 asm volatile("s_waitcnt vmcnt(0)" ::: "memory")

  GU_STB(0, 0, 0); GU_STB(0, 0, 1);
  GU_STA(0, 0, 0); GU_STA(0, 0, 1);
  GU_STB(1, 1, 0); GU_STB(1, 1, 1);
  GU_STA(1, 1, 0);
  GU_VM6;
  GU_BAR;

#pragma unroll 1
  for (int n = 0; n < 7; n++) {
    int tO = 2 * n + 1, tE2 = 2 * n + 2, tO2 = 2 * n + 3;
    GU_LDA(0, 0); GU_LDB(0, 0, b0); GU_STA(1, tO, 1);
    GU_BAR; GU_LGKM0; GU_MM(0, 0, b0); GU_BAR;
    GU_LDB(0, 2, b1);
    GU_BAR; GU_LGKM0; GU_MM(0, 2, b1); GU_BAR;
    GU_LDA(0, 4); GU_STB(0, tE2, 0);
    GU_BAR; GU_LGKM0; GU_MM(4, 0, b0); GU_BAR;
    GU_STB(0, tE2, 1); GU_STA(0, tE2, 0);
    GU_VM6;
    GU_BAR; GU_LGKM0; GU_MM(4, 2, b1); GU_BAR;
    GU_LDA(1, 0); GU_LDB(1, 0, b0); GU_STA(0, tE2, 1);
    GU_BAR; GU_LGKM0; GU_MM(0, 0, b0); GU_BAR;
    GU_LDB(1, 2, b1);
    GU_BAR; GU_LGKM0; GU_MM(0, 2, b1); GU_BAR;
    GU_LDA(1, 4); GU_STB(1, tO2, 0);
    GU_BAR; GU_LGKM0; GU_MM(4, 0, b0); GU_BAR;
    GU_STB(1, tO2, 1); GU_STA(1, tO2, 0);
    GU_VM6;
    GU_BAR; GU_LGKM0; GU_MM(4, 2, b1); GU_BAR;
  }
  GU_LDA(0, 0); GU_LDB(0, 0, b0); GU_STA(1, 15, 1);
  GU_BAR; GU_LGKM0; GU_MM(0, 0, b0); GU_BAR;
  GU_LDB(0, 2, b1);
  GU_BAR; GU_LGKM0; GU_MM(0, 2, b1); GU_BAR;
  GU_LDA(0, 4);
  GU_BAR; GU_LGKM0; GU_MM(4, 0, b0); GU_BAR;
  GU_VM0;
  GU_BAR; GU_LGKM0; GU_MM(4, 2, b1); GU_BAR;
  GU_LDA(1, 0); GU_LDB(1, 0, b0);
  GU_BAR; GU_LGKM0; GU_MM(0, 0, b0); GU_BAR;
  GU_LDB(1, 2, b1);
  GU_BAR; GU_LGKM0; GU_MM(0, 2, b1); GU_BAR;
  GU_LDA(1, 4);
  GU_BAR; GU_LGKM0; GU_MM(4, 0, b0); GU_BAR;
  GU_MM(4, 2, b1);

#undef GU_LDA
#undef GU_LDB
#undef GU_MM
#undef GU_STA
#undef GU_STB
#undef GU_AS
#undef GU_BS
#undef GU_BAR
#undef GU_LGKM0
#undef GU_VM6
#undef GU_VM0

#pragma unroll
  for (int i = 0; i < 8; i++) {
    int row = m0 + wm * 128 + i * 16 + quad * 4;
#pragma unroll
    for (int r = 0; r < 4; r++) {
#pragma unroll
      for (int jj = 0; jj < 2; jj++) {
        float g = acc[i][2 * jj][r];
        float u = acc[i][2 * jj + 1][r];
        int colL = n0l + (wn * 2 + jj) * 16 + fr;
        Cb[(size_t)(row + r) * FFN_ + colL] = f2bf(g / (1.f + __expf(-g)) * u);
      }
    }
  }
}

// ---------------------------------------------------------------------------
// MFMA flash attention, no-max softmax; Q pre-roped+pre-scaled bf16 [T][1024].
// ---------------------------------------------------------------------------
__global__ __launch_bounds__(256) void attn_mfma(const unsigned short* __restrict__ qb,
                                                 const unsigned short* __restrict__ Kb,
                                                 const unsigned short* __restrict__ Vt,
                                                 unsigned short* __restrict__ ctx) {
  __shared__ unsigned short Ks[64 * 128];
  __shared__ unsigned short Vs[128 * 64];
  __shared__ unsigned short Ps[4][16 * 72];
  int id = blockIdx.x;
  int bh = id & 15;
  int p_ = id >> 4;
  int qt = (p_ < 16) ? p_ : 47 - p_;
  int b = bh >> 3, h = bh & 7;
  int bk = b * KVH_ + (h >> 2);
  int q0 = qt * 64;
  int t = threadIdx.x, lane = t & 63, w = t >> 6;
  int fr = lane & 15, quad = lane >> 4;

  int pos = q0 + w * 16 + fr;
  const unsigned short* qrow = qb + (size_t)(b * L_ + pos) * 1024 + h * HD_;
  bf16x8 qf[4];
#pragma unroll
  for (int kb = 0; kb < 4; kb++)
    qf[kb] = __builtin_bit_cast(bf16x8, *(const ushortx8*)(qrow + kb * 32 + quad * 8));

  floatx4 o_acc[8];
#pragma unroll
  for (int nt = 0; nt < 8; nt++) o_acc[nt] = (floatx4){0.f, 0.f, 0.f, 0.f};
  float l_r[4] = {0.f, 0.f, 0.f, 0.f};
  unsigned short* Psw = Ps[w];
  const unsigned short* kgb = Kb + (size_t)bk * L_ * HD_;
  const unsigned short* vgb = Vt + (size_t)bk * HD_ * L_;
  int rowg0 = q0 + w * 16 + quad * 4;

  for (int kt = 0; kt <= qt; kt++) {
    int kstart = kt * 64;
    bool diag = (kt == qt);
    __syncthreads();
    const unsigned short* ksrc = kgb + (size_t)kstart * HD_;
#pragma unroll
    for (int it = 0; it < 4; it++) {
      int sl = it * 4 + w;
      gload_lds16(ksrc + sl * 512 + lane * 8, Ks + sl * 512);
    }
#pragma unroll
    for (int it = 0; it < 4; it++) {
      int sl = it * 4 + w;
      gload_lds16(vgb + (size_t)(sl * 8 + (lane >> 3)) * L_ + kstart + (lane & 7) * 8,
                  Vs + sl * 512);
    }
    __syncthreads();

    floatx4 s_acc[4];
#pragma unroll
    for (int jt = 0; jt < 4; jt++) s_acc[jt] = (floatx4){0.f, 0.f, 0.f, 0.f};
#pragma unroll
    for (int kb = 0; kb < 4; kb++) {
#pragma unroll
      for (int jt = 0; jt < 4; jt++) {
        bf16x8 kf = __builtin_bit_cast(
            bf16x8, *(const ushortx8*)(Ks + (jt * 16 + fr) * 128 +
                                       (((kb * 4 + quad) ^ fr) * 8)));
        s_acc[jt] = __builtin_amdgcn_mfma_f32_16x16x32_bf16(qf[kb], kf, s_acc[jt], 0, 0, 0);
      }
    }

#pragma unroll
    for (int jt = 0; jt < 4; jt++) {
#pragma unroll
      for (int r = 0; r < 4; r++) {
        float pp;
        if (diag) {
          int keyg = kstart + jt * 16 + fr;
          pp = (keyg <= rowg0 + r) ? __expf(s_acc[jt][r]) : 0.f;
        } else {
          pp = __expf(s_acc[jt][r]);
        }
        l_r[r] += pp;
        Psw[(quad * 4 + r) * 72 + jt * 16 + fr] = f2bf(pp);
      }
    }
    bf16x8 pf0 = __builtin_bit_cast(bf16x8, *(const ushortx8*)(Psw + fr * 72 + quad * 8));
    bf16x8 pf1 =
        __builtin_bit_cast(bf16x8, *(const ushortx8*)(Psw + fr * 72 + 32 + quad * 8));
#pragma unroll
    for (int nt = 0; nt < 8; nt++) {
      bf16x8 vf0 = __builtin_bit_cast(
          bf16x8,
          *(const ushortx8*)(Vs + (nt * 16 + fr) * 64 + ((quad ^ (fr & 7)) * 8)));
      bf16x8 vf1 = __builtin_bit_cast(
          bf16x8,
          *(const ushortx8*)(Vs + (nt * 16 + fr) * 64 + (((4 + quad) ^ (fr & 7)) * 8)));
      o_acc[nt] = __builtin_amdgcn_mfma_f32_16x16x32_bf16(pf0, vf0, o_acc[nt], 0, 0, 0);
      o_acc[nt] = __builtin_amdgcn_mfma_f32_16x16x32_bf16(pf1, vf1, o_acc[nt], 0, 0, 0);
    }
  }

#pragma unroll
  for (int r = 0; r < 4; r++) {
    l_r[r] += __shfl_xor(l_r[r], 1);
    l_r[r] += __shfl_xor(l_r[r], 2);
    l_r[r] += __shfl_xor(l_r[r], 4);
    l_r[r] += __shfl_xor(l_r[r], 8);
  }

  unsigned short* ob =
      ctx + (size_t)(b * L_ + q0 + w * 16 + quad * 4) * 1024 + h * HD_ + fr;
#pragma unroll
  for (int r = 0; r < 4; r++) {
    float inv = 1.f / l_r[r];
    unsigned short* orow = ob + (size_t)r * 1024;
#pragma unroll
    for (int nt = 0; nt < 8; nt++) orow[nt * 16] = f2bf(o_acc[nt][r] * inv);
  }
}

// ---------------------------------------------------------------------------
extern "C" void kernel_launch(void* const* d_in, const int* in_sizes, int n_in,
                              void* d_out, int out_size, void* d_ws, size_t ws_size,
                              hipStream_t stream) {
  const float* x    = (const float*)d_in[0];
  const float* ln1w = (const float*)d_in[1];
  const float* wq   = (const float*)d_in[2];
  const float* wk   = (const float*)d_in[3];
  const float* wvp  = (const float*)d_in[4];
  const float* wo   = (const float*)d_in[5];
  const float* ln2w = (const float*)d_in[6];
  const float* wg   = (const float*)d_in[7];
  const float* wu   = (const float*)d_in[8];
  const float* wd   = (const float*)d_in[9];
  float* out = (float*)d_out;
  char* ws = (char*)d_ws;

  // workspace layout (bytes), ~92 MB total:
  unsigned short* wT = (unsigned short*)ws;                       // 30,408,704 B
  unsigned short* wqkvT = wT;                                     // [1536][1024]
  unsigned short* woT = wT + 1572864;                             // [1024][1024]
  unsigned short* wgT = wT + 2621440;                             // [4096][1024]
  unsigned short* wuT = wT + 6815744;                             // [4096][1024]
  unsigned short* wdT = wT + 11010048;                            // [1024][4096]
  unsigned short* h_bf = (unsigned short*)(ws + 30408704);        // 8 MB (ctx_bf reuse)
  unsigned short* qb = (unsigned short*)(ws + 38797312);          // [4096][1024] roped Q, 8 MB
  float* rope_tab = (float*)(ws + 47185920);                      // 1 MB sin/cos table
  unsigned short* h2_bf = (unsigned short*)(ws + 51380224);       // 8 MB
  unsigned short* Kb = (unsigned short*)(ws + 59768832);          // 2 MB (attn phase)
  unsigned short* Vt = (unsigned short*)(ws + 61865984);          // 2 MB (attn phase)
  unsigned short* gu = (unsigned short*)(ws + 59768832);          // 32 MB (FFN phase)
  unsigned short* ctx_bf = h_bf;

  dim3 blk(256);

  // 1. weight transposes + rmsnorm1 + rope sin/cos table (512 blocks)
  prep_all<<<3712 + T_ + 512, blk, 0, stream>>>(wq, wk, wvp, wo, wg, wu, wd, wT,
                                                x, ln1w, h_bf, rope_tab);
  // 2. fused QKV GEMM (BK=128) + rope(Q,K via table) + V transpose
  gemm_qkv<<<dim3(12, 64), blk, 0, stream>>>(h_bf, wqkvT, qb, Kb, Vt, rope_tab);
  // 3. attention (no-max softmax, Q pre-roped)
  attn_mfma<<<512, blk, 0, stream>>>(qb, Kb, Vt, ctx_bf);
  // 4. out = ctx @ wo + x   (64x128 tile; row-fastest grid for A-panel L2 reuse)
  gemm_bf16<1, 4><<<dim3(64, 8), blk, 0, stream>>>(ctx_bf, woT, x, out, T_, 1024, 1024);
  // 5. rmsnorm2 on out
  rmsnorm_bf16_kernel<<<T_, blk, 0, stream>>>(out, ln2w, h2_bf);
  // 6. gate+up fused: 8-phase counted-vmcnt (best measured variant)
  gemm_gateup8p<<<dim3(32, 16), dim3(512), 0, stream>>>(h2_bf, wgT, wuT, gu);
  // 7. out += gu @ wd — row-fastest grid: A (32MB) fetched ~once, B (8MB) streams
  gemm_bf16<2, 4><<<dim3(64, 8), blk, 0, stream>>>(gu, wdT, nullptr, out, T_, 1024, FFN_);
}